// Round 2
// baseline (404.940 us; speedup 1.0000x reference)
//
#include <hip/hip_runtime.h>
#include <hip/hip_bf16.h>
#include <math.h>

#define Tn   8192
#define Hn   1024
#define En   8
#define DFFn 4096

typedef __attribute__((ext_vector_type(8))) short bf16x8;  // 8 bf16 = 4 VGPRs
typedef __attribute__((ext_vector_type(4))) float f32x4;

static __device__ inline unsigned short f2bf(float f) {
    __hip_bfloat16 h = __float2bfloat16(f);
    return __builtin_bit_cast(unsigned short, h);
}

// ---------------- gate + x->bf16 conversion ----------------
// 512 blocks x 256 threads; one wave per token, stride 2048 (4 toks/wave).
// Lane l covers float4 chunk h4 = j*64+l (h = 4*h4..4*h4+3).
__global__ __launch_bounds__(256) void gate_convert(
    const float* __restrict__ x, const float* __restrict__ gW,
    const float* __restrict__ gb, unsigned short* __restrict__ xbf,
    float* __restrict__ tokw, float* __restrict__ load_sum,
    int* __restrict__ counts)
{
    __shared__ float s_load[En];
    __shared__ int   s_cnt[En];
    const int tid = threadIdx.x;
    if (tid < En) { s_load[tid] = 0.f; s_cnt[tid] = 0; }
    __syncthreads();

    const int lane = tid & 63;
    const int wv   = tid >> 6;

    for (int tok = blockIdx.x * 4 + wv; tok < Tn; tok += 2048) {
        const float4* xr = (const float4*)(x + (size_t)tok * Hn);
        float acc[8] = {0.f,0.f,0.f,0.f,0.f,0.f,0.f,0.f};
        #pragma unroll
        for (int j = 0; j < Hn / 256; ++j) {           // 4 iterations
            int h4 = j * 64 + lane;
            float4 xv = xr[h4];
            ushort4 pk;
            pk.x = f2bf(xv.x); pk.y = f2bf(xv.y);
            pk.z = f2bf(xv.z); pk.w = f2bf(xv.w);
            ((ushort4*)xbf)[(size_t)tok * (Hn / 4) + h4] = pk;
            const float* wr = gW + (size_t)h4 * 4 * En;   // 4 rows of gW
            float xs[4] = {xv.x, xv.y, xv.z, xv.w};
            #pragma unroll
            for (int c = 0; c < 4; ++c)
                #pragma unroll
                for (int e = 0; e < 8; ++e)
                    acc[e] += xs[c] * wr[c * 8 + e];
        }
        #pragma unroll
        for (int e = 0; e < 8; ++e) {
            float v = acc[e];
            #pragma unroll
            for (int off = 32; off > 0; off >>= 1) v += __shfl_xor(v, off, 64);
            acc[e] = v + gb[e];
        }
        if (lane == 0) {
            #pragma unroll
            for (int e = 0; e < 8; ++e) atomicAdd(&s_load[e], acc[e]);
            int i1 = 0; float v1 = acc[0];
            #pragma unroll
            for (int e = 1; e < 8; ++e) if (acc[e] > v1) { v1 = acc[e]; i1 = e; }
            int i2 = -1; float v2 = -3.0e38f;
            #pragma unroll
            for (int e = 0; e < 8; ++e) if (e != i1 && acc[e] > v2) { v2 = acc[e]; i2 = e; }
            atomicAdd(&s_cnt[i1], 1);
            atomicAdd(&s_cnt[i2], 1);
            float e2 = __expf(v2 - v1);
            float t  = 1.0f + e2;
            tokw[tok] = 1.0f / t + e2 / t;   // softmax(top2).sum()
        }
    }
    __syncthreads();
    if (tid < En) {
        atomicAdd(&load_sum[tid], s_load[tid]);
        atomicAdd(&counts[tid],   s_cnt[tid]);
    }
}

// ---------------- aux loss + counts into output tail ----------------
__global__ void finalize(const float* __restrict__ load_sum,
                         const int* __restrict__ counts,
                         float* __restrict__ out_tail)
{
    if (threadIdx.x == 0) {
        float aux = 0.f;
        #pragma unroll
        for (int e = 0; e < En; ++e) {
            float m = load_sum[e] * (1.0f / (float)Tn);
            aux += m * m;
        }
        out_tail[0] = aux;
        #pragma unroll
        for (int e = 0; e < En; ++e) out_tail[1 + e] = (float)counts[e];
    }
}

// ---------------- W [K][N] fp32 -> Wt [N][K] bf16 ----------------
__global__ __launch_bounds__(256) void transpose_cast(
    const float* __restrict__ src, __hip_bfloat16* __restrict__ dst,
    int Kd, int Nd)
{
    __shared__ float tile[32][33];
    const int n0 = blockIdx.x * 32, k0 = blockIdx.y * 32;
    const int tx = threadIdx.x & 31, ty = threadIdx.x >> 5;  // ty: 0..7
    #pragma unroll
    for (int r = 0; r < 32; r += 8)
        tile[ty + r][tx] = src[(size_t)(k0 + ty + r) * Nd + n0 + tx];
    __syncthreads();
    #pragma unroll
    for (int r = 0; r < 32; r += 8)
        dst[(size_t)(n0 + ty + r) * Kd + k0 + tx] = __float2bfloat16(tile[tx][ty + r]);
}

// ---------------- m97-style bf16 GEMM, C = epilogue(A @ Bt^T + bias) ------
// A  : [M][Kfull] bf16 row-major ; Bt : [N][Kfull] bf16 row-major
// Grid.z = number of K-splits; each handles Ksplit of Kfull.
// EPI==0: C = bf16( gelu_tanh(v + bias) )            (hdd; grid.z==1)
// EPI==1: C +=atomic fp32( (v + bias?z0) * tokw[row] ) (final out; C pre-zeroed)
template<int EPI>
__global__ __launch_bounds__(256) void gemm_bt(
    const __hip_bfloat16* __restrict__ A,
    const __hip_bfloat16* __restrict__ Bt,
    const float* __restrict__ bias,
    const float* __restrict__ tokw,
    void* __restrict__ C, int M, int N, int Kfull, int Ksplit)
{
    __shared__ __hip_bfloat16 sA[128 * 32];   // no padding: global_load_lds layout
    __shared__ __hip_bfloat16 sB[128 * 32];

    const int tid  = threadIdx.x;
    const int lane = tid & 63;
    const int wv   = tid >> 6;
    const int wm   = (wv >> 1) * 64;
    const int wn   = (wv & 1) * 64;
    const int m0   = blockIdx.y * 128, n0 = blockIdx.x * 128;
    const int kbeg = blockIdx.z * Ksplit;

    f32x4 acc[4][4];
    const f32x4 zero = {0.f, 0.f, 0.f, 0.f};
    #pragma unroll
    for (int i = 0; i < 4; ++i)
        #pragma unroll
        for (int j = 0; j < 4; ++j) acc[i][j] = zero;

    const int r0 = tid >> 2;
    const int kc = (tid & 3) * 8;
    const __hip_bfloat16* gA = A  + (size_t)(m0 + r0) * Kfull + kc;
    const __hip_bfloat16* gB = Bt + (size_t)(n0 + r0) * Kfull + kc;
    const size_t half = (size_t)64 * Kfull;

    const int fr = lane & 15;
    const int fk = (lane >> 4) * 8;

    for (int k0 = kbeg; k0 < kbeg + Ksplit; k0 += 32) {
        __syncthreads();
        __builtin_amdgcn_global_load_lds(
            (const __attribute__((address_space(1))) void*)(gA + k0),
            (__attribute__((address_space(3))) void*)(sA + tid * 8), 16, 0, 0);
        __builtin_amdgcn_global_load_lds(
            (const __attribute__((address_space(1))) void*)(gA + half + k0),
            (__attribute__((address_space(3))) void*)(sA + 2048 + tid * 8), 16, 0, 0);
        __builtin_amdgcn_global_load_lds(
            (const __attribute__((address_space(1))) void*)(gB + k0),
            (__attribute__((address_space(3))) void*)(sB + tid * 8), 16, 0, 0);
        __builtin_amdgcn_global_load_lds(
            (const __attribute__((address_space(1))) void*)(gB + half + k0),
            (__attribute__((address_space(3))) void*)(sB + 2048 + tid * 8), 16, 0, 0);
        __syncthreads();

        bf16x8 af[4], bfr[4];
        #pragma unroll
        for (int mi = 0; mi < 4; ++mi)
            af[mi] = *(const bf16x8*)(sA + (wm + mi * 16 + fr) * 32 + fk);
        #pragma unroll
        for (int ni = 0; ni < 4; ++ni)
            bfr[ni] = *(const bf16x8*)(sB + (wn + ni * 16 + fr) * 32 + fk);
        #pragma unroll
        for (int mi = 0; mi < 4; ++mi)
            #pragma unroll
            for (int ni = 0; ni < 4; ++ni)
                acc[mi][ni] = __builtin_amdgcn_mfma_f32_16x16x32_bf16(
                    af[mi], bfr[ni], acc[mi][ni], 0, 0, 0);
    }

    // epilogue: C/D layout col = lane&15, row = (lane>>4)*4 + reg
    const bool add_bias = (EPI == 0) || (blockIdx.z == 0);
    #pragma unroll
    for (int mi = 0; mi < 4; ++mi) {
        #pragma unroll
        for (int ni = 0; ni < 4; ++ni) {
            const int col   = n0 + wn + ni * 16 + (lane & 15);
            const int rbase = m0 + wm + mi * 16 + (lane >> 4) * 4;
            const float bv  = add_bias ? bias[col] : 0.f;
            #pragma unroll
            for (int i = 0; i < 4; ++i) {
                const int row = rbase + i;
                float v = acc[mi][ni][i] + bv;
                if (EPI == 0) {
                    // gelu tanh-form via sigmoid: gelu(v) ~= v * sigmoid(2u)
                    float u = 0.7978845608028654f * (v + 0.044715f * v * v * v);
                    float g = v / (1.0f + __expf(-2.0f * u));
                    ((__hip_bfloat16*)C)[(size_t)row * N + col] = __float2bfloat16(g);
                } else {
                    unsafeAtomicAdd(&((float*)C)[(size_t)row * N + col],
                                    v * tokw[row]);
                }
            }
        }
    }
}

extern "C" void kernel_launch(void* const* d_in, const int* in_sizes, int n_in,
                              void* d_out, int out_size, void* d_ws, size_t ws_size,
                              hipStream_t stream)
{
    const float* x  = (const float*)d_in[0];
    const float* gW = (const float*)d_in[1];
    const float* gb = (const float*)d_in[2];
    const float* W1 = (const float*)d_in[3];
    const float* b1 = (const float*)d_in[4];
    const float* W2 = (const float*)d_in[5];
    const float* b2 = (const float*)d_in[6];
    float* out = (float*)d_out;

    char* ws = (char*)d_ws;
    __hip_bfloat16* xbf = (__hip_bfloat16*)ws;  ws += (size_t)Tn * Hn * 2;     // 16 MB
    __hip_bfloat16* W1t = (__hip_bfloat16*)ws;  ws += (size_t)Hn * DFFn * 2;   //  8 MB
    __hip_bfloat16* W2t = (__hip_bfloat16*)ws;  ws += (size_t)Hn * DFFn * 2;   //  8 MB
    __hip_bfloat16* hdd = (__hip_bfloat16*)ws;  ws += (size_t)Tn * DFFn * 2;   // 64 MB
    float* tokw     = (float*)ws;               ws += (size_t)Tn * 4;          // 32 KB
    float* load_sum = (float*)ws;               ws += En * 4;
    int*   counts   = (int*)ws;                 ws += En * 4;

    hipMemsetAsync(load_sum, 0, En * 4 * 2, stream);          // load_sum + counts
    hipMemsetAsync(out, 0, (size_t)Tn * Hn * 4, stream);      // split-K accum target

    transpose_cast<<<dim3(DFFn / 32, Hn / 32), 256, 0, stream>>>(W1, W1t, Hn, DFFn);
    transpose_cast<<<dim3(Hn / 32, DFFn / 32), 256, 0, stream>>>(W2, W2t, DFFn, Hn);
    gate_convert<<<512, 256, 0, stream>>>(x, gW, gb, (unsigned short*)xbf,
                                          tokw, load_sum, counts);
    finalize<<<1, 64, 0, stream>>>(load_sum, counts, out + (size_t)Tn * Hn);

    // hdd = gelu(x @ W1 + b1)            [8192 x 4096]
    gemm_bt<0><<<dim3(DFFn / 128, Tn / 128, 1), 256, 0, stream>>>(
        xbf, W1t, b1, nullptr, hdd, Tn, DFFn, Hn, Hn);
    // out += (hdd @ W2 + b2) * tokw[row] [8192 x 1024], split-K=2
    gemm_bt<1><<<dim3(Hn / 128, Tn / 128, 2), 256, 0, stream>>>(
        hdd, W2t, b2, tokw, out, Tn, Hn, DFFn, DFFn / 2);
}

// Round 3
// 331.455 us; speedup vs baseline: 1.2217x; 1.2217x over previous
//
#include <hip/hip_runtime.h>
#include <hip/hip_bf16.h>
#include <math.h>

#define Tn   8192
#define Hn   1024
#define En   8
#define DFFn 4096

typedef __attribute__((ext_vector_type(8))) short bf16x8;  // 8 bf16 = 4 VGPRs
typedef __attribute__((ext_vector_type(4))) float f32x4;

static __device__ inline unsigned short f2bf(float f) {
    __hip_bfloat16 h = __float2bfloat16(f);
    return __builtin_bit_cast(unsigned short, h);
}

// ---------------- gate + x->bf16 conversion ----------------
// 512 blocks x 256 threads; one wave per token, stride 2048 (4 toks/wave).
__global__ __launch_bounds__(256) void gate_convert(
    const float* __restrict__ x, const float* __restrict__ gW,
    const float* __restrict__ gb, unsigned short* __restrict__ xbf,
    float* __restrict__ tokw, float* __restrict__ load_sum,
    int* __restrict__ counts)
{
    __shared__ float s_load[En];
    __shared__ int   s_cnt[En];
    const int tid = threadIdx.x;
    if (tid < En) { s_load[tid] = 0.f; s_cnt[tid] = 0; }
    __syncthreads();

    const int lane = tid & 63;
    const int wv   = tid >> 6;

    for (int tok = blockIdx.x * 4 + wv; tok < Tn; tok += 2048) {
        const float4* xr = (const float4*)(x + (size_t)tok * Hn);
        float acc[8] = {0.f,0.f,0.f,0.f,0.f,0.f,0.f,0.f};
        #pragma unroll
        for (int j = 0; j < Hn / 256; ++j) {           // 4 iterations
            int h4 = j * 64 + lane;
            float4 xv = xr[h4];
            ushort4 pk;
            pk.x = f2bf(xv.x); pk.y = f2bf(xv.y);
            pk.z = f2bf(xv.z); pk.w = f2bf(xv.w);
            ((ushort4*)xbf)[(size_t)tok * (Hn / 4) + h4] = pk;
            const float* wr = gW + (size_t)h4 * 4 * En;   // 4 rows of gW
            float xs[4] = {xv.x, xv.y, xv.z, xv.w};
            #pragma unroll
            for (int c = 0; c < 4; ++c)
                #pragma unroll
                for (int e = 0; e < 8; ++e)
                    acc[e] += xs[c] * wr[c * 8 + e];
        }
        #pragma unroll
        for (int e = 0; e < 8; ++e) {
            float v = acc[e];
            #pragma unroll
            for (int off = 32; off > 0; off >>= 1) v += __shfl_xor(v, off, 64);
            acc[e] = v + gb[e];
        }
        if (lane == 0) {
            #pragma unroll
            for (int e = 0; e < 8; ++e) atomicAdd(&s_load[e], acc[e]);
            int i1 = 0; float v1 = acc[0];
            #pragma unroll
            for (int e = 1; e < 8; ++e) if (acc[e] > v1) { v1 = acc[e]; i1 = e; }
            int i2 = -1; float v2 = -3.0e38f;
            #pragma unroll
            for (int e = 0; e < 8; ++e) if (e != i1 && acc[e] > v2) { v2 = acc[e]; i2 = e; }
            atomicAdd(&s_cnt[i1], 1);
            atomicAdd(&s_cnt[i2], 1);
            float e2 = __expf(v2 - v1);
            float t  = 1.0f + e2;
            tokw[tok] = 1.0f / t + e2 / t;   // softmax(top2).sum()
        }
    }
    __syncthreads();
    if (tid < En) {
        atomicAdd(&load_sum[tid], s_load[tid]);
        atomicAdd(&counts[tid],   s_cnt[tid]);
    }
}

// ---------------- aux loss + counts into output tail ----------------
__global__ void finalize(const float* __restrict__ load_sum,
                         const int* __restrict__ counts,
                         float* __restrict__ out_tail)
{
    if (threadIdx.x == 0) {
        float aux = 0.f;
        #pragma unroll
        for (int e = 0; e < En; ++e) {
            float m = load_sum[e] * (1.0f / (float)Tn);
            aux += m * m;
        }
        out_tail[0] = aux;
        #pragma unroll
        for (int e = 0; e < En; ++e) out_tail[1 + e] = (float)counts[e];
    }
}

// ---------------- W [K][N] fp32 -> Wt [N][K] bf16 ----------------
__global__ __launch_bounds__(256) void transpose_cast(
    const float* __restrict__ src, __hip_bfloat16* __restrict__ dst,
    int Kd, int Nd)
{
    __shared__ float tile[32][33];
    const int n0 = blockIdx.x * 32, k0 = blockIdx.y * 32;
    const int tx = threadIdx.x & 31, ty = threadIdx.x >> 5;  // ty: 0..7
    #pragma unroll
    for (int r = 0; r < 32; r += 8)
        tile[ty + r][tx] = src[(size_t)(k0 + ty + r) * Nd + n0 + tx];
    __syncthreads();
    #pragma unroll
    for (int r = 0; r < 32; r += 8)
        dst[(size_t)(n0 + ty + r) * Kd + k0 + tx] = __float2bfloat16(tile[tx][ty + r]);
}

// ---------------- m97-style bf16 GEMM, C = epilogue(A @ Bt^T + bias) ------
// A : [M][K] bf16 row-major ; Bt : [N][K] bf16 row-major.
// 1D grid, XCD-aware swizzle: all nx x-blocks that share an A-row-stripe get
// ids congruent mod 8 -> same XCD, dispatched within 8 ids of each other, so
// each A stripe is fetched into exactly one XCD's L2.
// EPI==0: C = bf16( gelu_tanh(v + bias) )   (hdd)
// EPI==1: C = fp32( (v + bias) * tokw[row] ) (final output)
template<int EPI>
__global__ __launch_bounds__(256) void gemm_bt(
    const __hip_bfloat16* __restrict__ A,
    const __hip_bfloat16* __restrict__ Bt,
    const float* __restrict__ bias,
    const float* __restrict__ tokw,
    void* __restrict__ C, int N, int K, int nxlog2)
{
    __shared__ __hip_bfloat16 sA[128 * 32];   // no padding: global_load_lds layout
    __shared__ __hip_bfloat16 sB[128 * 32];

    const int tid  = threadIdx.x;
    const int lane = tid & 63;
    const int wv   = tid >> 6;
    const int wm   = (wv >> 1) * 64;
    const int wn   = (wv & 1) * 64;

    // XCD swizzle: id%8 = xcd; within an XCD, x varies fastest.
    const int id     = blockIdx.x;
    const int xcd    = id & 7;
    const int slot   = id >> 3;
    const int bx     = slot & ((1 << nxlog2) - 1);
    const int ylocal = slot >> nxlog2;
    const int y_per  = (int)((gridDim.x >> 3) >> nxlog2);   // ny/8
    const int by     = xcd * y_per + ylocal;

    const int m0 = by * 128, n0 = bx * 128;

    f32x4 acc[4][4];
    const f32x4 zero = {0.f, 0.f, 0.f, 0.f};
    #pragma unroll
    for (int i = 0; i < 4; ++i)
        #pragma unroll
        for (int j = 0; j < 4; ++j) acc[i][j] = zero;

    const int r0 = tid >> 2;
    const int kc = (tid & 3) * 8;
    const __hip_bfloat16* gA = A  + (size_t)(m0 + r0) * K + kc;
    const __hip_bfloat16* gB = Bt + (size_t)(n0 + r0) * K + kc;
    const size_t half = (size_t)64 * K;

    const int fr = lane & 15;
    const int fk = (lane >> 4) * 8;

    for (int k0 = 0; k0 < K; k0 += 32) {
        __syncthreads();
        __builtin_amdgcn_global_load_lds(
            (const __attribute__((address_space(1))) void*)(gA + k0),
            (__attribute__((address_space(3))) void*)(sA + tid * 8), 16, 0, 0);
        __builtin_amdgcn_global_load_lds(
            (const __attribute__((address_space(1))) void*)(gA + half + k0),
            (__attribute__((address_space(3))) void*)(sA + 2048 + tid * 8), 16, 0, 0);
        __builtin_amdgcn_global_load_lds(
            (const __attribute__((address_space(1))) void*)(gB + k0),
            (__attribute__((address_space(3))) void*)(sB + tid * 8), 16, 0, 0);
        __builtin_amdgcn_global_load_lds(
            (const __attribute__((address_space(1))) void*)(gB + half + k0),
            (__attribute__((address_space(3))) void*)(sB + 2048 + tid * 8), 16, 0, 0);
        __syncthreads();

        bf16x8 af[4], bfr[4];
        #pragma unroll
        for (int mi = 0; mi < 4; ++mi)
            af[mi] = *(const bf16x8*)(sA + (wm + mi * 16 + fr) * 32 + fk);
        #pragma unroll
        for (int ni = 0; ni < 4; ++ni)
            bfr[ni] = *(const bf16x8*)(sB + (wn + ni * 16 + fr) * 32 + fk);
        #pragma unroll
        for (int mi = 0; mi < 4; ++mi)
            #pragma unroll
            for (int ni = 0; ni < 4; ++ni)
                acc[mi][ni] = __builtin_amdgcn_mfma_f32_16x16x32_bf16(
                    af[mi], bfr[ni], acc[mi][ni], 0, 0, 0);
    }

    // epilogue: C/D layout col = lane&15, row = (lane>>4)*4 + reg
    #pragma unroll
    for (int mi = 0; mi < 4; ++mi) {
        #pragma unroll
        for (int ni = 0; ni < 4; ++ni) {
            const int col   = n0 + wn + ni * 16 + (lane & 15);
            const int rbase = m0 + wm + mi * 16 + (lane >> 4) * 4;
            const float bv  = bias[col];
            #pragma unroll
            for (int i = 0; i < 4; ++i) {
                const int row = rbase + i;
                float v = acc[mi][ni][i] + bv;
                if (EPI == 0) {
                    // gelu tanh-form via sigmoid: gelu(v) ~= v * sigmoid(2u)
                    float u = 0.7978845608028654f * (v + 0.044715f * v * v * v);
                    float g = v / (1.0f + __expf(-2.0f * u));
                    ((__hip_bfloat16*)C)[(size_t)row * N + col] = __float2bfloat16(g);
                } else {
                    ((float*)C)[(size_t)row * N + col] = v * tokw[row];
                }
            }
        }
    }
}

extern "C" void kernel_launch(void* const* d_in, const int* in_sizes, int n_in,
                              void* d_out, int out_size, void* d_ws, size_t ws_size,
                              hipStream_t stream)
{
    const float* x  = (const float*)d_in[0];
    const float* gW = (const float*)d_in[1];
    const float* gb = (const float*)d_in[2];
    const float* W1 = (const float*)d_in[3];
    const float* b1 = (const float*)d_in[4];
    const float* W2 = (const float*)d_in[5];
    const float* b2 = (const float*)d_in[6];
    float* out = (float*)d_out;

    char* ws = (char*)d_ws;
    __hip_bfloat16* xbf = (__hip_bfloat16*)ws;  ws += (size_t)Tn * Hn * 2;     // 16 MB
    __hip_bfloat16* W1t = (__hip_bfloat16*)ws;  ws += (size_t)Hn * DFFn * 2;   //  8 MB
    __hip_bfloat16* W2t = (__hip_bfloat16*)ws;  ws += (size_t)Hn * DFFn * 2;   //  8 MB
    __hip_bfloat16* hdd = (__hip_bfloat16*)ws;  ws += (size_t)Tn * DFFn * 2;   // 64 MB
    float* tokw     = (float*)ws;               ws += (size_t)Tn * 4;          // 32 KB
    float* load_sum = (float*)ws;               ws += En * 4;
    int*   counts   = (int*)ws;                 ws += En * 4;

    hipMemsetAsync(load_sum, 0, En * 4 * 2, stream);   // load_sum + counts

    transpose_cast<<<dim3(DFFn / 32, Hn / 32), 256, 0, stream>>>(W1, W1t, Hn, DFFn);
    transpose_cast<<<dim3(Hn / 32, DFFn / 32), 256, 0, stream>>>(W2, W2t, DFFn, Hn);
    gate_convert<<<512, 256, 0, stream>>>(x, gW, gb, (unsigned short*)xbf,
                                          tokw, load_sum, counts);
    finalize<<<1, 64, 0, stream>>>(load_sum, counts, out + (size_t)Tn * Hn);

    // hdd = gelu(x @ W1 + b1)            [8192 x 4096]; nx=32 -> nxlog2=5
    gemm_bt<0><<<(DFFn / 128) * (Tn / 128), 256, 0, stream>>>(
        xbf, W1t, b1, nullptr, hdd, DFFn, Hn, 5);
    // out = (hdd @ W2 + b2) * tokw[row]  [8192 x 1024]; nx=8 -> nxlog2=3
    gemm_bt<1><<<(Hn / 128) * (Tn / 128), 256, 0, stream>>>(
        hdd, W2t, b2, tokw, out, Hn, DFFn, 3);
}